// Round 1
// baseline (138.494 us; speedup 1.0000x reference)
//
#include <hip/hip_runtime.h>
#include <hip/hip_bf16.h>
#include <cstdint>
#include <cstddef>

#define VOCAB   32000
#define HIDDEN  1024
#define BATCH   128
#define SEQ     2048
#define NEG_INF -1.0e9f

#define BM 128
#define BN 128
#define BK 64
#define KSTEPS (VOCAB / BK)   // 500 (exact: 32000 = 500*64)
#define NT (HIDDEN / BN)      // 8
#define KG 64                 // split-K groups -> 512 workgroups (2/CU)

typedef __attribute__((ext_vector_type(8))) short  short8;
typedef __attribute__((ext_vector_type(4))) float  f32x4;

static __device__ __forceinline__ ushort f2bf(float f) {
  uint32_t u = __float_as_uint(f);
  u += 0x7FFFu + ((u >> 16) & 1u);   // round-to-nearest-even
  return (ushort)(u >> 16);
}

// ---------------------------------------------------------------------------
// Kernel A: per-row masked softmax over SEQ + scatter-add into pooled [B,V]
// ---------------------------------------------------------------------------
__global__ __launch_bounds__(256) void softmax_scatter_kernel(
    const int* __restrict__ x, const float* __restrict__ w_attn,
    const float* __restrict__ b_attn, float* __restrict__ pooled) {
  const int b   = blockIdx.x;
  const int tid = threadIdx.x;
  const int* xr = x + (size_t)b * SEQ;
  const float ba = b_attn[0];

  int   xi[8];
  float lg[8];
  float m = -3.0e38f;
#pragma unroll
  for (int i = 0; i < 8; ++i) {
    int t = xr[tid + 256 * i];
    xi[i] = t;
    float v = (t > 0) ? (w_attn[t] + ba) : NEG_INF;
    lg[i] = v;
    m = fmaxf(m, v);
  }
#pragma unroll
  for (int off = 32; off; off >>= 1) m = fmaxf(m, __shfl_xor(m, off));

  __shared__ float redm[4], reds[4];
  if ((tid & 63) == 0) redm[tid >> 6] = m;
  __syncthreads();
  const float M = fmaxf(fmaxf(redm[0], redm[1]), fmaxf(redm[2], redm[3]));

  float e[8];
  float s = 0.f;
#pragma unroll
  for (int i = 0; i < 8; ++i) {
    float v = (xi[i] > 0) ? __expf(lg[i] - M) : 0.f;
    e[i] = v;
    s += v;
  }
#pragma unroll
  for (int off = 32; off; off >>= 1) s += __shfl_xor(s, off);
  if ((tid & 63) == 0) reds[tid >> 6] = s;
  __syncthreads();
  const float S   = reds[0] + reds[1] + reds[2] + reds[3];
  const float inv = 1.0f / S;

  float* pr = pooled + (size_t)b * VOCAB;
#pragma unroll
  for (int i = 0; i < 8; ++i)
    if (xi[i] > 0) atomicAdd(pr + xi[i], e[i] * inv);
}

// ---------------------------------------------------------------------------
// Kernel B: split-K bf16 MFMA GEMM: partials[g] += pooled[128,Kg] @ w1[Kg,1024]
// 128x128 tile, 4 waves (2x2), 16x16x32 bf16 MFMA, f32->bf16 convert on load.
// ---------------------------------------------------------------------------
template <bool ATOMIC>
__global__ __launch_bounds__(256, 2) void gemm_kernel(
    const float* __restrict__ pooled, const float* __restrict__ w1,
    float* __restrict__ hout) {
  const int tid  = threadIdx.x;
  const int lane = tid & 63;
  const int wid  = tid >> 6;
  const int bid  = blockIdx.x;
  const int nt   = bid & 7;       // N tile
  const int g    = bid >> 3;      // K group (0..63)
  const int n0   = nt * BN;

  int kb, ke;                      // 500 K-steps split: 52 groups of 8, 12 of 7
  if (g < 52) { kb = g * 8;                ke = kb + 8; }
  else        { kb = 416 + (g - 52) * 7;   ke = kb + 7; }

  __shared__ __align__(16) ushort As[BM][BK + 8];   // pad 16B: stride 144B
  __shared__ __align__(16) ushort Bs[BK][BN + 4];   // pad  8B: stride 264B

  const int wm = wid >> 1, wn = wid & 1;            // 2x2 wave grid, 64x64 each
  f32x4 acc[4][4];
#pragma unroll
  for (int i = 0; i < 4; ++i)
#pragma unroll
    for (int j = 0; j < 4; ++j) acc[i][j] = (f32x4){0.f, 0.f, 0.f, 0.f};

  const int a_r = tid >> 4;          // 0..15
  const int a_c = (tid & 15) * 4;    // 0..60
  const int b_k = tid >> 5;          // 0..7
  const int b_n = (tid & 31) * 4;    // 0..124
  const int fr  = lane & 15;
  const int fq  = lane >> 4;

  for (int kt = kb; kt < ke; ++kt) {
    const int k0 = kt * BK;
    __syncthreads();
    // stage A: pooled rows 0..127, cols k0..k0+63 (f32 -> bf16)
#pragma unroll
    for (int i = 0; i < 8; ++i) {
      const int row = a_r + i * 16;
      float4 v = *(const float4*)(pooled + (size_t)row * VOCAB + k0 + a_c);
      ushort4 b4 = {f2bf(v.x), f2bf(v.y), f2bf(v.z), f2bf(v.w)};
      *(ushort4*)(&As[row][a_c]) = b4;
    }
    // stage B: w1 rows k0..k0+63, cols n0..n0+127
#pragma unroll
    for (int i = 0; i < 8; ++i) {
      const int kr = b_k + i * 8;
      float4 v = *(const float4*)(w1 + (size_t)(k0 + kr) * HIDDEN + n0 + b_n);
      ushort4 b4 = {f2bf(v.x), f2bf(v.y), f2bf(v.z), f2bf(v.w)};
      *(ushort4*)(&Bs[kr][b_n]) = b4;
    }
    __syncthreads();

#pragma unroll
    for (int ks = 0; ks < 2; ++ks) {
      const int kk = ks * 32;
      short8 af[4], bf[4];
#pragma unroll
      for (int mi = 0; mi < 4; ++mi) {
        const int row = wm * 64 + mi * 16 + fr;
        af[mi] = *(const short8*)(&As[row][kk + fq * 8]);
      }
#pragma unroll
      for (int ni = 0; ni < 4; ++ni) {
        const int n = wn * 64 + ni * 16 + fr;
        short8 t;
#pragma unroll
        for (int j = 0; j < 8; ++j) t[j] = (short)Bs[kk + fq * 8 + j][n];
        bf[ni] = t;
      }
#pragma unroll
      for (int mi = 0; mi < 4; ++mi)
#pragma unroll
        for (int ni = 0; ni < 4; ++ni)
          acc[mi][ni] = __builtin_amdgcn_mfma_f32_16x16x32_bf16(
              af[mi], bf[ni], acc[mi][ni], 0, 0, 0);
    }
  }

  // epilogue: C/D mapping col = lane&15, row = (lane>>4)*4 + r  [m89-verified]
#pragma unroll
  for (int mi = 0; mi < 4; ++mi) {
#pragma unroll
    for (int ni = 0; ni < 4; ++ni) {
      const int col = n0 + wn * 64 + ni * 16 + fr;
#pragma unroll
      for (int r = 0; r < 4; ++r) {
        const int row = wm * 64 + mi * 16 + fq * 4 + r;
        if (ATOMIC) {
          atomicAdd(&hout[(size_t)row * HIDDEN + col], acc[mi][ni][r]);
        } else {
          hout[((size_t)g * BATCH + row) * HIDDEN + col] = acc[mi][ni][r];
        }
      }
    }
  }
}

// ---------------------------------------------------------------------------
// Kernel C: h = relu(sum_p partials + b1); out = log_softmax(h @ w2 + b2)
// ---------------------------------------------------------------------------
__global__ __launch_bounds__(256) void finalize_kernel(
    const float* __restrict__ parts, int P, const float* __restrict__ b1,
    const float* __restrict__ w2, const float* __restrict__ b2,
    float* __restrict__ out) {
  const int b = blockIdx.x, tid = threadIdx.x;
  float s0 = 0.f, s1 = 0.f;
  for (int j = tid; j < HIDDEN; j += 256) {
    float h = 0.f;
    for (int p = 0; p < P; ++p)
      h += parts[((size_t)p * BATCH + b) * HIDDEN + j];
    h += b1[j];
    h = fmaxf(h, 0.f);
    s0 += h * w2[2 * j];
    s1 += h * w2[2 * j + 1];
  }
#pragma unroll
  for (int off = 32; off; off >>= 1) {
    s0 += __shfl_xor(s0, off);
    s1 += __shfl_xor(s1, off);
  }
  __shared__ float r0[4], r1[4];
  if ((tid & 63) == 0) { r0[tid >> 6] = s0; r1[tid >> 6] = s1; }
  __syncthreads();
  if (tid == 0) {
    float l0 = r0[0] + r0[1] + r0[2] + r0[3] + b2[0];
    float l1 = r1[0] + r1[1] + r1[2] + r1[3] + b2[1];
    float mx = fmaxf(l0, l1);
    float lse = mx + logf(__expf(l0 - mx) + __expf(l1 - mx));
    out[2 * b]     = l0 - lse;
    out[2 * b + 1] = l1 - lse;
  }
}

// ---------------------------------------------------------------------------
extern "C" void kernel_launch(void* const* d_in, const int* in_sizes, int n_in,
                              void* d_out, int out_size, void* d_ws,
                              size_t ws_size, hipStream_t stream) {
  const int*   x      = (const int*)  d_in[0];
  const float* w_attn = (const float*)d_in[1];
  const float* b_attn = (const float*)d_in[2];
  const float* w1     = (const float*)d_in[3];
  const float* b1     = (const float*)d_in[4];
  const float* w2     = (const float*)d_in[5];
  const float* b2     = (const float*)d_in[6];
  float* out = (float*)d_out;

  const size_t pooledBytes = (size_t)BATCH * VOCAB * sizeof(float);        // 16.38 MB
  const size_t partBytes   = (size_t)KG * BATCH * HIDDEN * sizeof(float);  // 33.55 MB

  float* pooled = (float*)d_ws;
  float* parts  = (float*)((char*)d_ws + pooledBytes);

  if (ws_size >= pooledBytes + partBytes) {
    // deterministic split-K partials path
    hipMemsetAsync(d_ws, 0, pooledBytes, stream);
    softmax_scatter_kernel<<<BATCH, 256, 0, stream>>>(x, w_attn, b_attn, pooled);
    gemm_kernel<false><<<NT * KG, 256, 0, stream>>>(pooled, w1, parts);
    finalize_kernel<<<BATCH, 256, 0, stream>>>(parts, KG, b1, w2, b2, out);
  } else {
    // small-ws fallback: atomic accumulate into h [128,1024] right after pooled
    hipMemsetAsync(d_ws, 0, pooledBytes + (size_t)BATCH * HIDDEN * sizeof(float),
                   stream);
    softmax_scatter_kernel<<<BATCH, 256, 0, stream>>>(x, w_attn, b_attn, pooled);
    gemm_kernel<true><<<NT * KG, 256, 0, stream>>>(pooled, w1, parts);
    finalize_kernel<<<BATCH, 256, 0, stream>>>(parts, 1, b1, w2, b2, out);
  }
}

// Round 2
// 81.171 us; speedup vs baseline: 1.7062x; 1.7062x over previous
//
#include <hip/hip_runtime.h>
#include <hip/hip_bf16.h>
#include <cstdint>
#include <cstddef>

#define VOCAB   32000
#define HIDDEN  1024
#define BATCH   128
#define SEQ     2048
#define NEG_INF -1.0e9f

#define BM 128
#define BN 128
#define BK 64
#define KSTEPS (VOCAB / BK)   // 500 (exact: 32000 = 500*64)
#define NT (HIDDEN / BN)      // 8
#define KG 64                 // split-K groups -> 512 workgroups (2/CU)

typedef __attribute__((ext_vector_type(8))) short  short8;
typedef __attribute__((ext_vector_type(4))) float  f32x4;

static __device__ __forceinline__ ushort f2bf(float f) {
  uint32_t u = __float_as_uint(f);
  u += 0x7FFFu + ((u >> 16) & 1u);   // round-to-nearest-even
  return (ushort)(u >> 16);
}
static __device__ __forceinline__ float bf2f(ushort u) {
  return __uint_as_float(((uint32_t)u) << 16);
}

// ---------------------------------------------------------------------------
// Zero kernel: grid-stride float4 fill (the rocclr fill kernel ran at 221 GB/s
// for this 16 MB buffer -> 74 us; this one should do ~3-4 us)
// ---------------------------------------------------------------------------
__global__ __launch_bounds__(256) void zero_kernel(float4* __restrict__ p,
                                                   int n4) {
  int i = blockIdx.x * 256 + threadIdx.x;
  const int stride = gridDim.x * 256;
  for (; i < n4; i += stride) p[i] = (float4){0.f, 0.f, 0.f, 0.f};
}

// ---------------------------------------------------------------------------
// Kernel A: per-row masked softmax over SEQ + scatter-add into pooled [B,V]
// ---------------------------------------------------------------------------
__global__ __launch_bounds__(256) void softmax_scatter_kernel(
    const int* __restrict__ x, const float* __restrict__ w_attn,
    const float* __restrict__ b_attn, float* __restrict__ pooled) {
  const int b   = blockIdx.x;
  const int tid = threadIdx.x;
  const int* xr = x + (size_t)b * SEQ;
  const float ba = b_attn[0];

  int   xi[8];
  float lg[8];
  float m = -3.0e38f;
#pragma unroll
  for (int i = 0; i < 8; ++i) {
    int t = xr[tid + 256 * i];
    xi[i] = t;
    float v = (t > 0) ? (w_attn[t] + ba) : NEG_INF;
    lg[i] = v;
    m = fmaxf(m, v);
  }
#pragma unroll
  for (int off = 32; off; off >>= 1) m = fmaxf(m, __shfl_xor(m, off));

  __shared__ float redm[4], reds[4];
  if ((tid & 63) == 0) redm[tid >> 6] = m;
  __syncthreads();
  const float M = fmaxf(fmaxf(redm[0], redm[1]), fmaxf(redm[2], redm[3]));

  float e[8];
  float s = 0.f;
#pragma unroll
  for (int i = 0; i < 8; ++i) {
    float v = (xi[i] > 0) ? __expf(lg[i] - M) : 0.f;
    e[i] = v;
    s += v;
  }
#pragma unroll
  for (int off = 32; off; off >>= 1) s += __shfl_xor(s, off);
  if ((tid & 63) == 0) reds[tid >> 6] = s;
  __syncthreads();
  const float S   = reds[0] + reds[1] + reds[2] + reds[3];
  const float inv = 1.0f / S;

  float* pr = pooled + (size_t)b * VOCAB;
#pragma unroll
  for (int i = 0; i < 8; ++i)
    if (xi[i] > 0) atomicAdd(pr + xi[i], e[i] * inv);
}

// ---------------------------------------------------------------------------
// Kernel B: split-K bf16 MFMA GEMM: partials[g] = pooled[128,Kg] @ w1[Kg,1024]
// 128x128 tile, 4 waves (2x2), 16x16x32 bf16 MFMA, f32->bf16 convert on load.
// ATOMIC=false: writes bf16 partials [KG][BATCH][HIDDEN].
// ATOMIC=true : f32 atomicAdd into h [BATCH][HIDDEN] (small-ws fallback).
// ---------------------------------------------------------------------------
template <bool ATOMIC>
__global__ __launch_bounds__(256, 2) void gemm_kernel(
    const float* __restrict__ pooled, const float* __restrict__ w1,
    void* __restrict__ hout_v) {
  const int tid  = threadIdx.x;
  const int lane = tid & 63;
  const int wid  = tid >> 6;
  const int bid  = blockIdx.x;
  const int nt   = bid & 7;       // N tile
  const int g    = bid >> 3;      // K group (0..63)
  const int n0   = nt * BN;

  int kb, ke;                      // 500 K-steps split: 52 groups of 8, 12 of 7
  if (g < 52) { kb = g * 8;                ke = kb + 8; }
  else        { kb = 416 + (g - 52) * 7;   ke = kb + 7; }

  __shared__ __align__(16) ushort As[BM][BK + 8];   // pad 16B: stride 144B
  __shared__ __align__(16) ushort Bs[BK][BN + 4];   // pad  8B: stride 264B

  const int wm = wid >> 1, wn = wid & 1;            // 2x2 wave grid, 64x64 each
  f32x4 acc[4][4];
#pragma unroll
  for (int i = 0; i < 4; ++i)
#pragma unroll
    for (int j = 0; j < 4; ++j) acc[i][j] = (f32x4){0.f, 0.f, 0.f, 0.f};

  const int a_r = tid >> 4;          // 0..15
  const int a_c = (tid & 15) * 4;    // 0..60
  const int b_k = tid >> 5;          // 0..7
  const int b_n = (tid & 31) * 4;    // 0..124
  const int fr  = lane & 15;
  const int fq  = lane >> 4;

  for (int kt = kb; kt < ke; ++kt) {
    const int k0 = kt * BK;
    __syncthreads();
    // stage A: pooled rows 0..127, cols k0..k0+63 (f32 -> bf16)
#pragma unroll
    for (int i = 0; i < 8; ++i) {
      const int row = a_r + i * 16;
      float4 v = *(const float4*)(pooled + (size_t)row * VOCAB + k0 + a_c);
      ushort4 b4 = {f2bf(v.x), f2bf(v.y), f2bf(v.z), f2bf(v.w)};
      *(ushort4*)(&As[row][a_c]) = b4;
    }
    // stage B: w1 rows k0..k0+63, cols n0..n0+127
#pragma unroll
    for (int i = 0; i < 8; ++i) {
      const int kr = b_k + i * 8;
      float4 v = *(const float4*)(w1 + (size_t)(k0 + kr) * HIDDEN + n0 + b_n);
      ushort4 b4 = {f2bf(v.x), f2bf(v.y), f2bf(v.z), f2bf(v.w)};
      *(ushort4*)(&Bs[kr][b_n]) = b4;
    }
    __syncthreads();

#pragma unroll
    for (int ks = 0; ks < 2; ++ks) {
      const int kk = ks * 32;
      short8 af[4], bf[4];
#pragma unroll
      for (int mi = 0; mi < 4; ++mi) {
        const int row = wm * 64 + mi * 16 + fr;
        af[mi] = *(const short8*)(&As[row][kk + fq * 8]);
      }
#pragma unroll
      for (int ni = 0; ni < 4; ++ni) {
        const int n = wn * 64 + ni * 16 + fr;
        short8 t;
#pragma unroll
        for (int j = 0; j < 8; ++j) t[j] = (short)Bs[kk + fq * 8 + j][n];
        bf[ni] = t;
      }
#pragma unroll
      for (int mi = 0; mi < 4; ++mi)
#pragma unroll
        for (int ni = 0; ni < 4; ++ni)
          acc[mi][ni] = __builtin_amdgcn_mfma_f32_16x16x32_bf16(
              af[mi], bf[ni], acc[mi][ni], 0, 0, 0);
    }
  }

  // epilogue: C/D mapping col = lane&15, row = (lane>>4)*4 + r  [m89-verified]
#pragma unroll
  for (int mi = 0; mi < 4; ++mi) {
#pragma unroll
    for (int ni = 0; ni < 4; ++ni) {
      const int col = n0 + wn * 64 + ni * 16 + fr;
#pragma unroll
      for (int r = 0; r < 4; ++r) {
        const int row = wm * 64 + mi * 16 + fq * 4 + r;
        if (ATOMIC) {
          atomicAdd((float*)hout_v + (size_t)row * HIDDEN + col,
                    acc[mi][ni][r]);
        } else {
          ((ushort*)hout_v)[((size_t)g * BATCH + row) * HIDDEN + col] =
              f2bf(acc[mi][ni][r]);
        }
      }
    }
  }
}

// ---------------------------------------------------------------------------
// Kernel C (bf16 partials): h = relu(sum_p parts + b1);
//                           out = log_softmax(h @ w2 + b2)
// 128 blocks x 256 threads; each thread owns 4 hidden columns (ushort4 loads).
// ---------------------------------------------------------------------------
__global__ __launch_bounds__(256) void finalize_bf_kernel(
    const ushort* __restrict__ parts, const float* __restrict__ b1,
    const float* __restrict__ w2, const float* __restrict__ b2,
    float* __restrict__ out) {
  const int b = blockIdx.x, tid = threadIdx.x;
  const int j0 = tid * 4;  // 256*4 == HIDDEN
  float h0 = 0.f, h1 = 0.f, h2 = 0.f, h3 = 0.f;
  for (int p = 0; p < KG; ++p) {
    ushort4 v = *(const ushort4*)(parts + ((size_t)(p * BATCH + b) << 10) + j0);
    h0 += bf2f(v.x); h1 += bf2f(v.y); h2 += bf2f(v.z); h3 += bf2f(v.w);
  }
  float hv0 = fmaxf(h0 + b1[j0 + 0], 0.f);
  float hv1 = fmaxf(h1 + b1[j0 + 1], 0.f);
  float hv2 = fmaxf(h2 + b1[j0 + 2], 0.f);
  float hv3 = fmaxf(h3 + b1[j0 + 3], 0.f);
  float4 wa = *(const float4*)(w2 + 2 * j0);
  float4 wb = *(const float4*)(w2 + 2 * j0 + 4);
  float s0 = hv0 * wa.x + hv1 * wa.z + hv2 * wb.x + hv3 * wb.z;
  float s1 = hv0 * wa.y + hv1 * wa.w + hv2 * wb.y + hv3 * wb.w;
#pragma unroll
  for (int off = 32; off; off >>= 1) {
    s0 += __shfl_xor(s0, off);
    s1 += __shfl_xor(s1, off);
  }
  __shared__ float r0[4], r1[4];
  if ((tid & 63) == 0) { r0[tid >> 6] = s0; r1[tid >> 6] = s1; }
  __syncthreads();
  if (tid == 0) {
    float l0 = r0[0] + r0[1] + r0[2] + r0[3] + b2[0];
    float l1 = r1[0] + r1[1] + r1[2] + r1[3] + b2[1];
    float mx = fmaxf(l0, l1);
    float lse = mx + logf(__expf(l0 - mx) + __expf(l1 - mx));
    out[2 * b]     = l0 - lse;
    out[2 * b + 1] = l1 - lse;
  }
}

// f32 fallback finalize (small-ws atomic path)
__global__ __launch_bounds__(256) void finalize_f32_kernel(
    const float* __restrict__ hbuf, const float* __restrict__ b1,
    const float* __restrict__ w2, const float* __restrict__ b2,
    float* __restrict__ out) {
  const int b = blockIdx.x, tid = threadIdx.x;
  const int j0 = tid * 4;
  float4 h = *(const float4*)(hbuf + ((size_t)b << 10) + j0);
  float hv0 = fmaxf(h.x + b1[j0 + 0], 0.f);
  float hv1 = fmaxf(h.y + b1[j0 + 1], 0.f);
  float hv2 = fmaxf(h.z + b1[j0 + 2], 0.f);
  float hv3 = fmaxf(h.w + b1[j0 + 3], 0.f);
  float4 wa = *(const float4*)(w2 + 2 * j0);
  float4 wb = *(const float4*)(w2 + 2 * j0 + 4);
  float s0 = hv0 * wa.x + hv1 * wa.z + hv2 * wb.x + hv3 * wb.z;
  float s1 = hv0 * wa.y + hv1 * wa.w + hv2 * wb.y + hv3 * wb.w;
#pragma unroll
  for (int off = 32; off; off >>= 1) {
    s0 += __shfl_xor(s0, off);
    s1 += __shfl_xor(s1, off);
  }
  __shared__ float r0[4], r1[4];
  if ((tid & 63) == 0) { r0[tid >> 6] = s0; r1[tid >> 6] = s1; }
  __syncthreads();
  if (tid == 0) {
    float l0 = r0[0] + r0[1] + r0[2] + r0[3] + b2[0];
    float l1 = r1[0] + r1[1] + r1[2] + r1[3] + b2[1];
    float mx = fmaxf(l0, l1);
    float lse = mx + logf(__expf(l0 - mx) + __expf(l1 - mx));
    out[2 * b]     = l0 - lse;
    out[2 * b + 1] = l1 - lse;
  }
}

// ---------------------------------------------------------------------------
extern "C" void kernel_launch(void* const* d_in, const int* in_sizes, int n_in,
                              void* d_out, int out_size, void* d_ws,
                              size_t ws_size, hipStream_t stream) {
  const int*   x      = (const int*)  d_in[0];
  const float* w_attn = (const float*)d_in[1];
  const float* b_attn = (const float*)d_in[2];
  const float* w1     = (const float*)d_in[3];
  const float* b1     = (const float*)d_in[4];
  const float* w2     = (const float*)d_in[5];
  const float* b2     = (const float*)d_in[6];
  float* out = (float*)d_out;

  const size_t pooledBytes = (size_t)BATCH * VOCAB * sizeof(float);         // 16.38 MB
  const size_t partBytes   = (size_t)KG * BATCH * HIDDEN * sizeof(ushort);  // 16.78 MB

  float*  pooled = (float*)d_ws;
  ushort* parts  = (ushort*)((char*)d_ws + pooledBytes);

  if (ws_size >= pooledBytes + partBytes) {
    // deterministic split-K bf16-partials path
    zero_kernel<<<2048, 256, 0, stream>>>((float4*)pooled,
                                          (int)(pooledBytes / 16));
    softmax_scatter_kernel<<<BATCH, 256, 0, stream>>>(x, w_attn, b_attn, pooled);
    gemm_kernel<false><<<NT * KG, 256, 0, stream>>>(pooled, w1, parts);
    finalize_bf_kernel<<<BATCH, 256, 0, stream>>>(parts, b1, w2, b2, out);
  } else {
    // small-ws fallback: f32 atomic accumulate into h [128,1024] after pooled
    float* hbuf = (float*)((char*)d_ws + pooledBytes);
    const size_t hBytes = (size_t)BATCH * HIDDEN * sizeof(float);
    zero_kernel<<<2048, 256, 0, stream>>>((float4*)d_ws,
                                          (int)((pooledBytes + hBytes) / 16));
    softmax_scatter_kernel<<<BATCH, 256, 0, stream>>>(x, w_attn, b_attn, pooled);
    gemm_kernel<true><<<NT * KG, 256, 0, stream>>>(pooled, w1, hbuf);
    finalize_f32_kernel<<<BATCH, 256, 0, stream>>>(hbuf, b1, w2, b2, out);
  }
}